// Round 1
// 487.192 us; speedup vs baseline: 1.3152x; 1.3152x over previous
//
#include <hip/hip_runtime.h>
#include <math.h>

#define Bb 4
#define Cc 8
#define Ss 512
#define Ee 512
#define Hh 8
#define HDd 64
#define LOCALW 32
#define NTOK (Bb*Cc*Ss)   // 16384 rows
#define RS 40             // P-scratch row stride (shorts): 80 B -> b64 writes 2-way, b128 reads 2-way

typedef __attribute__((ext_vector_type(8))) __bf16 bf16x8;
typedef __attribute__((ext_vector_type(4))) float floatx4;
typedef __attribute__((ext_vector_type(4))) unsigned short ushort4v;

__device__ __forceinline__ unsigned short f2bf(float f) {
  union { float f; unsigned int i; } x; x.f = f;
  unsigned int r = x.i + 0x7fffu + ((x.i >> 16) & 1u);  // RNE
  return (unsigned short)(r >> 16);
}

// exp that tolerates -inf - -inf = NaN inputs (whole-quad masked rows): clamps to ~0
__device__ __forceinline__ float sexp(float x) { return __expf(fmaxf(x, -80.0f)); }

// Convert q,k,v fp32 -> bf16 (blockIdx.y selects tensor)
__global__ __launch_bounds__(256) void cvt3_f32_bf16(
    const float4* __restrict__ s0, const float4* __restrict__ s1, const float4* __restrict__ s2,
    ushort4v* __restrict__ d0, ushort4v* __restrict__ d1, ushort4v* __restrict__ d2, int n4)
{
  const float4* src = (blockIdx.y == 0) ? s0 : (blockIdx.y == 1) ? s1 : s2;
  ushort4v*    dst  = (blockIdx.y == 0) ? d0 : (blockIdx.y == 1) ? d1 : d2;
  int idx = blockIdx.x * blockDim.x + threadIdx.x;
  int stride = gridDim.x * blockDim.x;
  for (int i = idx; i < n4; i += stride) {
    float4 v = src[i];
    ushort4v o;
    o[0] = f2bf(v.x); o[1] = f2bf(v.y); o[2] = f2bf(v.z); o[3] = f2bf(v.w);
    dst[i] = o;
  }
}

// Convert 4 weight matrices fp32 -> bf16
__global__ __launch_bounds__(256) void cvtW_f32_bf16(
    const float4* __restrict__ s0, const float4* __restrict__ s1,
    const float4* __restrict__ s2, const float4* __restrict__ s3,
    ushort4v* __restrict__ d0, ushort4v* __restrict__ d1,
    ushort4v* __restrict__ d2, ushort4v* __restrict__ d3, int n4)
{
  const float4* src = (blockIdx.y == 0) ? s0 : (blockIdx.y == 1) ? s1 : (blockIdx.y == 2) ? s2 : s3;
  ushort4v*    dst  = (blockIdx.y == 0) ? d0 : (blockIdx.y == 1) ? d1 : (blockIdx.y == 2) ? d2 : d3;
  int idx = blockIdx.x * blockDim.x + threadIdx.x;
  int stride = gridDim.x * blockDim.x;
  for (int i = idx; i < n4; i += stride) {
    float4 v = src[i];
    ushort4v o;
    o[0] = f2bf(v.x); o[1] = f2bf(v.y); o[2] = f2bf(v.z); o[3] = f2bf(v.w);
    dst[i] = o;
  }
}

// out[m,n] = sum_k X[m,k]*W[n,k] + bias[n].  LDS-staged (global_load_lds w=16),
// block tile 128x128, BK=64, 4 waves (wave tile 64x64 = 4x4 MFMA).
// blockIdx.z selects (X,W,bias,out) triple so all 3 projections ride one dispatch.
// LDS layout [row][chunk]: stored chunk c holds source chunk c ^ (row&7) -> ~conflict-free b128.
template <bool F32OUT>
__global__ __launch_bounds__(256, 4) void gemm_nt_bias3(
    const unsigned short* __restrict__ X0, const unsigned short* __restrict__ X1,
    const unsigned short* __restrict__ X2,
    const unsigned short* __restrict__ W0, const unsigned short* __restrict__ W1,
    const unsigned short* __restrict__ W2,
    const float* __restrict__ bias0, const float* __restrict__ bias1,
    const float* __restrict__ bias2,
    void* __restrict__ out0, void* __restrict__ out1, void* __restrict__ out2)
{
  const int z = blockIdx.z;
  const unsigned short* X = (z == 0) ? X0 : (z == 1) ? X1 : X2;
  const unsigned short* W = (z == 0) ? W0 : (z == 1) ? W1 : W2;
  const float* bias        = (z == 0) ? bias0 : (z == 1) ? bias1 : bias2;
  void* outv               = (z == 0) ? out0 : (z == 1) ? out1 : out2;

  __shared__ unsigned short As[128 * 64];   // 16 KB
  __shared__ unsigned short Bs[128 * 64];   // 16 KB

  const int K = Ee, N = Ee;
  const int lane = threadIdx.x & 63;
  const int wave = threadIdx.x >> 6;
  const int r16  = lane & 15;
  const int oct  = lane >> 4;
  const int m_blk = blockIdx.y * 128;
  const int n_blk = blockIdx.x * 128;
  const int wm = (wave >> 1) * 64;
  const int wn = (wave & 1) * 64;

  const int row8  = lane >> 3;
  const int chSt  = lane & 7;
  const int chSrc = chSt ^ row8;

  floatx4 acc[4][4];
  #pragma unroll
  for (int a = 0; a < 4; ++a)
    #pragma unroll
    for (int b = 0; b < 4; ++b)
      acc[a][b] = (floatx4)(0.0f);

  for (int kb = 0; kb < K; kb += 64) {
    __syncthreads();
    #pragma unroll
    for (int t = 0; t < 4; ++t) {
      const int rbase = t * 32 + wave * 8;
      const int arow = m_blk + rbase + row8;
      const int brow = n_blk + rbase + row8;
      __builtin_amdgcn_global_load_lds(
          (const __attribute__((address_space(1))) unsigned int*)(X + (size_t)arow * K + kb + chSrc * 8),
          (__attribute__((address_space(3))) unsigned int*)(As + rbase * 64), 16, 0, 0);
      __builtin_amdgcn_global_load_lds(
          (const __attribute__((address_space(1))) unsigned int*)(W + (size_t)brow * K + kb + chSrc * 8),
          (__attribute__((address_space(3))) unsigned int*)(Bs + rbase * 64), 16, 0, 0);
    }
    __syncthreads();

    #pragma unroll
    for (int s = 0; s < 2; ++s) {
      bf16x8 af[4], bfq[4];
      #pragma unroll
      for (int mi = 0; mi < 4; ++mi) {
        const int row = wm + mi * 16 + r16;
        af[mi] = *(const bf16x8*)(As + row * 64 + ((s * 4 + oct) ^ (r16 & 7)) * 8);
      }
      #pragma unroll
      for (int ni = 0; ni < 4; ++ni) {
        const int row = wn + ni * 16 + r16;
        bfq[ni] = *(const bf16x8*)(Bs + row * 64 + ((s * 4 + oct) ^ (r16 & 7)) * 8);
      }
      #pragma unroll
      for (int mi = 0; mi < 4; ++mi)
        #pragma unroll
        for (int ni = 0; ni < 4; ++ni)
          acc[mi][ni] = __builtin_amdgcn_mfma_f32_16x16x32_bf16(af[mi], bfq[ni], acc[mi][ni], 0, 0, 0);
    }
  }

  #pragma unroll
  for (int mi = 0; mi < 4; ++mi)
    #pragma unroll
    for (int ni = 0; ni < 4; ++ni)
      #pragma unroll
      for (int r = 0; r < 4; ++r) {
        const int m = m_blk + wm + mi * 16 + oct * 4 + r;
        const int n = n_blk + wn + ni * 16 + r16;
        const float val = acc[mi][ni][r] + bias[n];
        if (F32OUT) ((float*)outv)[(size_t)m * N + n] = val;
        else        ((unsigned short*)outv)[(size_t)m * N + n] = f2bf(val);
      }
}

// ============================= attn v2 ========================================
// Swapped-QK + two-pass online softmax. Per (b,h,c) slice: 2 blocks x 8 waves;
// wave handles stripe pair (rt0, 31-rt0), 16 q-rows each.
//
// Layout (swapped mfma(K,Q)): lane (r16,oct) owns row i=I+r16; reg r holds
// j = 16ct + 4oct + r (4 CONSECUTIVE j -> float4 attn stores; j%4==r so the
// strided mask collapses to "r==0 => j<=i", others window-only).
//
// Pass A: online max/sum only (no P-state array!) -> ~100 regs total ->
// __launch_bounds__(512,4) => 2 blocks/CU = 16 waves/CU (v1 held sc[32] =
// 128 VGPR + AGPR acc => 1 block/CU = 8 waves, Occupancy 19%).
// Pass B: recompute scores, p = exp(s + c), c = -m - log(l); nontemporal
// float4 attn stores; P->A-frag via 2x ds_write_b64 + 1x ds_read_b128 per jc.
// PV swapped (mfma(V^T,P)) -> ctx lands 4-consecutive-d per lane -> 8B stores.
//
// V^T staging: wave w owns d-rows w*8..w*8+7; lane packs j-pair into dword
// writes -> 2-way banks (v1: 2-byte scatter, ~16-way, ~3.7M conflict cycles).
__global__ __launch_bounds__(512, 4) void attn_kernel(
    const unsigned short* __restrict__ Q,
    const unsigned short* __restrict__ Kb,
    const unsigned short* __restrict__ V,
    float* __restrict__ attn_out,           // write-only
    unsigned short* __restrict__ ctx)
{
  __shared__ unsigned short VT[HDd][Ss];        // 64 KB, [d][j^((d&7)<<3)]
  __shared__ unsigned short scr[8][16 * RS];    // 10 KB per-wave P scratch

  const int slice = blockIdx.x;            // (b*H + h)*C + c
  const int c  = slice & (Cc - 1);
  const int bh = slice >> 3;
  const int h  = bh & (Hh - 1);
  const int b  = bh >> 3;
  const size_t tokBase  = (size_t)(b * Cc + c) * Ss;
  const size_t attnBase = (size_t)slice * Ss * Ss;

  const int tid  = threadIdx.x;
  const int lane = tid & 63;
  const int wave = tid >> 6;
  const int r16  = lane & 15;
  const int oct  = lane >> 4;
  unsigned short* sw = scr[wave];

  // ---- stage V^T: wave w -> d rows w*8..w*8+7; lane jp -> j pair (2jp,2jp+1)
  {
    const int d0 = wave * 8;
    const unsigned short* vbase = V + tokBase * Ee + h * HDd + d0;
    #pragma unroll
    for (int pass = 0; pass < 4; ++pass) {
      const int j0 = pass * 128 + lane * 2;
      const uint4 ra = *(const uint4*)(vbase + (size_t)j0 * Ee);
      const uint4 rb = *(const uint4*)(vbase + (size_t)(j0 + 1) * Ee);
      const unsigned int aw[4] = {ra.x, ra.y, ra.z, ra.w};
      const unsigned int bw[4] = {rb.x, rb.y, rb.z, rb.w};
      #pragma unroll
      for (int k = 0; k < 8; ++k) {
        const unsigned int av = (k & 1) ? (aw[k >> 1] >> 16) : (aw[k >> 1] & 0xffffu);
        const unsigned int bv = (k & 1) ? (bw[k >> 1] >> 16) : (bw[k >> 1] & 0xffffu);
        *(unsigned int*)(&VT[d0 + k][j0 ^ (k << 3)]) = av | (bv << 16);  // pair stays adjacent (swz flips bits>=3)
      }
    }
  }
  __syncthreads();

  const int rt0 = 2 * wave + blockIdx.y;   // 0..15
  for (int t = 0; t < 2; ++t) {
    const int rt = t ? (31 - rt0) : rt0;   // pair sums to 31 -> balanced waves
    const int I  = rt * 16;
    const int i  = I + r16;

    const unsigned short* qrow = Q + (tokBase + i) * Ee + h * HDd + oct * 8;
    const bf16x8 qa0 = *(const bf16x8*)(qrow);
    const bf16x8 qa1 = *(const bf16x8*)(qrow + 32);
    const unsigned short* kbase = Kb + (tokBase + r16) * Ee + h * HDd + oct * 8;
    const int ij0 = i - 4 * oct;           // di(r) = ij0 - 16ct - r

    // ---- pass A: online max/sum (natural-log domain), no score storage ----
    // far cts (ct <= rt-3): di >= 48 > 35 for all lanes -> only r==0 allowed,
    // and it's always allowed (j<i). Two interleaved states halve the dep chain.
    float m_a = -INFINITY, l_a = 0.0f, m_b = -INFINITY, l_b = 0.0f;
    const int farEnd = rt - 2;             // far region = [0, farEnd)
    int ct = 0;
    for (; ct + 1 < farEnd; ct += 2) {
      const unsigned short* kr0 = kbase + (size_t)ct * (16 * Ee);
      const unsigned short* kr1 = kbase + (size_t)(ct + 1) * (16 * Ee);
      const bf16x8 ka0 = *(const bf16x8*)(kr0);
      const bf16x8 ka1 = *(const bf16x8*)(kr0 + 32);
      const bf16x8 kc0 = *(const bf16x8*)(kr1);
      const bf16x8 kc1 = *(const bf16x8*)(kr1 + 32);
      floatx4 a = (floatx4)(0.0f), a2 = (floatx4)(0.0f);
      a  = __builtin_amdgcn_mfma_f32_16x16x32_bf16(ka0, qa0, a, 0, 0, 0);
      a  = __builtin_amdgcn_mfma_f32_16x16x32_bf16(ka1, qa1, a, 0, 0, 0);
      a2 = __builtin_amdgcn_mfma_f32_16x16x32_bf16(kc0, qa0, a2, 0, 0, 0);
      a2 = __builtin_amdgcn_mfma_f32_16x16x32_bf16(kc1, qa1, a2, 0, 0, 0);
      const float v0 = a[0] * 0.125f;
      const float w0 = a2[0] * 0.125f;
      float mn = fmaxf(m_a, v0);
      l_a = l_a * sexp(m_a - mn) + sexp(v0 - mn);
      m_a = mn;
      mn = fmaxf(m_b, w0);
      l_b = l_b * sexp(m_b - mn) + sexp(w0 - mn);
      m_b = mn;
    }
    for (; ct < farEnd; ++ct) {
      const unsigned short* krow = kbase + (size_t)ct * (16 * Ee);
      const bf16x8 kb0 = *(const bf16x8*)(krow);
      const bf16x8 kb1 = *(const bf16x8*)(krow + 32);
      floatx4 a = (floatx4)(0.0f);
      a = __builtin_amdgcn_mfma_f32_16x16x32_bf16(kb0, qa0, a, 0, 0, 0);
      a = __builtin_amdgcn_mfma_f32_16x16x32_bf16(kb1, qa1, a, 0, 0, 0);
      const float v0 = a[0] * 0.125f;
      const float mn = fmaxf(m_a, v0);
      l_a = l_a * sexp(m_a - mn) + sexp(v0 - mn);
      m_a = mn;
    }
    // near cts: full 4-value mask
    for (ct = (farEnd > 0 ? farEnd : 0); ct <= rt; ++ct) {
      const unsigned short* krow = kbase + (size_t)ct * (16 * Ee);
      const bf16x8 kb0 = *(const bf16x8*)(krow);
      const bf16x8 kb1 = *(const bf16x8*)(krow + 32);
      floatx4 a = (floatx4)(0.0f);
      a = __builtin_amdgcn_mfma_f32_16x16x32_bf16(kb0, qa0, a, 0, 0, 0);
      a = __builtin_amdgcn_mfma_f32_16x16x32_bf16(kb1, qa1, a, 0, 0, 0);
      const int dib = ij0 - 16 * ct;
      const float v0 = (dib >= 0)                   ? a[0] * 0.125f : -INFINITY;
      const float v1 = ((unsigned)(dib - 1) <= 32u) ? a[1] * 0.125f : -INFINITY;
      const float v2 = ((unsigned)(dib - 2) <= 32u) ? a[2] * 0.125f : -INFINITY;
      const float v3 = ((unsigned)(dib - 3) <= 32u) ? a[3] * 0.125f : -INFINITY;
      const float mx4 = fmaxf(fmaxf(v0, v1), fmaxf(v2, v3));
      const float mn = fmaxf(m_a, mx4);
      l_a = l_a * sexp(m_a - mn)
          + sexp(v0 - mn) + sexp(v1 - mn) + sexp(v2 - mn) + sexp(v3 - mn);
      m_a = mn;
    }
    // merge b-state, then across the 4 octs sharing this row (xor 16, 32)
    float m = fmaxf(m_a, m_b);
    float l = l_a * sexp(m_a - m) + l_b * sexp(m_b - m);
    #pragma unroll
    for (int msk = 16; msk <= 32; msk <<= 1) {
      const float mo = __shfl_xor(m, msk, 64);
      const float lo = __shfl_xor(l, msk, 64);
      const float mn = fmaxf(m, mo);
      l = l * sexp(m - mn) + lo * sexp(mo - mn);
      m = mn;
    }
    const float cc = -m - __logf(l);       // p = exp(s + cc), exact zeros when masked

    // ---- pass B: recompute scores, store attn (nt float4), feed PV ----
    const int jcMax = rt >> 1;
    floatx4 cacc[4];
    #pragma unroll
    for (int dt = 0; dt < 4; ++dt) cacc[dt] = (floatx4)(0.0f);
    float* attnRow = attn_out + attnBase + (size_t)i * Ss + oct * 4;
    unsigned short* swrow = sw + r16 * RS;

    for (int jc = 0; jc <= jcMax; ++jc) {
      #pragma unroll
      for (int h2 = 0; h2 < 2; ++h2) {
        const int ctp = 2 * jc + h2;
        float p0 = 0.0f, p1 = 0.0f, p2 = 0.0f, p3 = 0.0f;
        if (ctp <= rt) {
          const unsigned short* krow = kbase + (size_t)ctp * (16 * Ee);
          const bf16x8 kb0 = *(const bf16x8*)(krow);
          const bf16x8 kb1 = *(const bf16x8*)(krow + 32);
          floatx4 a = (floatx4)(0.0f);
          a = __builtin_amdgcn_mfma_f32_16x16x32_bf16(kb0, qa0, a, 0, 0, 0);
          a = __builtin_amdgcn_mfma_f32_16x16x32_bf16(kb1, qa1, a, 0, 0, 0);
          if (ctp < farEnd) {
            p0 = __expf(a[0] * 0.125f + cc);
          } else {
            const int dib = ij0 - 16 * ctp;
            if (dib >= 0)                   p0 = __expf(a[0] * 0.125f + cc);
            if ((unsigned)(dib - 1) <= 32u) p1 = __expf(a[1] * 0.125f + cc);
            if ((unsigned)(dib - 2) <= 32u) p2 = __expf(a[2] * 0.125f + cc);
            if ((unsigned)(dib - 3) <= 32u) p3 = __expf(a[3] * 0.125f + cc);
          }
        }
        __builtin_nontemporal_store((floatx4){p0, p1, p2, p3},
                                    (floatx4*)(attnRow + (size_t)ctp * 16));
        const unsigned int plo = (unsigned int)f2bf(p0) | ((unsigned int)f2bf(p1) << 16);
        const unsigned int phi = (unsigned int)f2bf(p2) | ((unsigned int)f2bf(p3) << 16);
        *(uint2*)(swrow + h2 * 16 + oct * 4) = make_uint2(plo, phi);
      }
      const bf16x8 pa = *(const bf16x8*)(swrow + oct * 8);
      #pragma unroll
      for (int dt = 0; dt < 4; ++dt) {
        const int d = dt * 16 + r16;
        const bf16x8 vb = *(const bf16x8*)(&VT[d][(jc * 32 + oct * 8) ^ ((d & 7) << 3)]);
        cacc[dt] = __builtin_amdgcn_mfma_f32_16x16x32_bf16(vb, pa, cacc[dt], 0, 0, 0);
      }
    }
    // zero tail beyond the causal stripe
    const floatx4 z4 = (floatx4)(0.0f);
    for (int ctz = 2 * (jcMax + 1); ctz < 32; ++ctz)
      __builtin_nontemporal_store(z4, (floatx4*)(attnRow + (size_t)ctz * 16));
    // ctx: lane holds 4 consecutive d per dt -> packed 8B stores
    #pragma unroll
    for (int dt = 0; dt < 4; ++dt) {
      const unsigned int lo = (unsigned int)f2bf(cacc[dt][0]) | ((unsigned int)f2bf(cacc[dt][1]) << 16);
      const unsigned int hi = (unsigned int)f2bf(cacc[dt][2]) | ((unsigned int)f2bf(cacc[dt][3]) << 16);
      *(uint2*)(ctx + (tokBase + i) * Ee + h * HDd + dt * 16 + oct * 4) = make_uint2(lo, hi);
    }
  }
}

extern "C" void kernel_launch(void* const* d_in, const int* in_sizes, int n_in,
                              void* d_out, int out_size, void* d_ws, size_t ws_size,
                              hipStream_t stream) {
  const float* query = (const float*)d_in[0];
  const float* key_  = (const float*)d_in[1];
  const float* value = (const float*)d_in[2];
  const float* Wq = (const float*)d_in[3];
  const float* bq = (const float*)d_in[4];
  const float* Wk = (const float*)d_in[5];
  const float* bk = (const float*)d_in[6];
  const float* Wv = (const float*)d_in[7];
  const float* bv = (const float*)d_in[8];
  const float* Wo = (const float*)d_in[9];
  const float* bo = (const float*)d_in[10];

  float* out  = (float*)d_out;                          // [B,C,S,E] fp32
  float* attn = out + (size_t)Bb*Cc*Ss*Ee;              // [B,H,C,S,S] fp32

  unsigned short* ws = (unsigned short*)d_ws;
  unsigned short* qb  = ws;
  unsigned short* kb  = qb  + (size_t)NTOK * Ee;
  unsigned short* vb  = kb  + (size_t)NTOK * Ee;
  unsigned short* Qw  = vb  + (size_t)NTOK * Ee;
  unsigned short* Kw  = Qw  + (size_t)NTOK * Ee;
  unsigned short* Vw  = Kw  + (size_t)NTOK * Ee;
  unsigned short* Cw  = Vw  + (size_t)NTOK * Ee;
  unsigned short* Wqb = Cw  + (size_t)NTOK * Ee;
  unsigned short* Wkb = Wqb + (size_t)Ee * Ee;
  unsigned short* Wvb = Wkb + (size_t)Ee * Ee;
  unsigned short* Wob = Wvb + (size_t)Ee * Ee;

  const int n4big = NTOK * Ee / 4;
  const int n4w   = Ee * Ee / 4;
  cvt3_f32_bf16<<<dim3(1024, 3), 256, 0, stream>>>(
      (const float4*)query, (const float4*)key_, (const float4*)value,
      (ushort4v*)qb, (ushort4v*)kb, (ushort4v*)vb, n4big);
  cvtW_f32_bf16<<<dim3(128, 4), 256, 0, stream>>>(
      (const float4*)Wq, (const float4*)Wk, (const float4*)Wv, (const float4*)Wo,
      (ushort4v*)Wqb, (ushort4v*)Wkb, (ushort4v*)Wvb, (ushort4v*)Wob, n4w);

  dim3 blk(256);
  // fused q/k/v projections: z = tensor index
  gemm_nt_bias3<false><<<dim3(Ee / 128, NTOK / 128, 3), blk, 0, stream>>>(
      qb, kb, vb, Wqb, Wkb, Wvb, bq, bk, bv, Qw, Kw, Vw);

  attn_kernel<<<dim3(Bb*Hh*Cc, 2), 512, 0, stream>>>(Qw, Kw, Vw, attn, Cw);

  gemm_nt_bias3<true><<<dim3(Ee / 128, NTOK / 128, 1), blk, 0, stream>>>(
      Cw, Cw, Cw, Wob, Wob, Wob, bo, bo, bo, out, out, out);
}

// Round 2
// 484.108 us; speedup vs baseline: 1.3236x; 1.0064x over previous
//
#include <hip/hip_runtime.h>
#include <math.h>

#define Bb 4
#define Cc 8
#define Ss 512
#define Ee 512
#define Hh 8
#define HDd 64
#define LOCALW 32
#define NTOK (Bb*Cc*Ss)   // 16384 rows
#define RS 40             // P-scratch row stride (shorts): 80 B -> b64 writes 2-way, b128 reads 2-way

typedef __attribute__((ext_vector_type(8))) __bf16 bf16x8;
typedef __attribute__((ext_vector_type(4))) float floatx4;
typedef __attribute__((ext_vector_type(4))) unsigned short ushort4v;

__device__ __forceinline__ unsigned short f2bf(float f) {
  union { float f; unsigned int i; } x; x.f = f;
  unsigned int r = x.i + 0x7fffu + ((x.i >> 16) & 1u);  // RNE
  return (unsigned short)(r >> 16);
}

// exp that tolerates -inf - -inf = NaN inputs (whole-quad masked rows): clamps to ~0
__device__ __forceinline__ float sexp(float x) { return __expf(fmaxf(x, -80.0f)); }

// Convert q,k,v fp32 -> bf16 (blockIdx.y selects tensor)
__global__ __launch_bounds__(256) void cvt3_f32_bf16(
    const float4* __restrict__ s0, const float4* __restrict__ s1, const float4* __restrict__ s2,
    ushort4v* __restrict__ d0, ushort4v* __restrict__ d1, ushort4v* __restrict__ d2, int n4)
{
  const float4* src = (blockIdx.y == 0) ? s0 : (blockIdx.y == 1) ? s1 : s2;
  ushort4v*    dst  = (blockIdx.y == 0) ? d0 : (blockIdx.y == 1) ? d1 : d2;
  int idx = blockIdx.x * blockDim.x + threadIdx.x;
  int stride = gridDim.x * blockDim.x;
  for (int i = idx; i < n4; i += stride) {
    float4 v = src[i];
    ushort4v o;
    o[0] = f2bf(v.x); o[1] = f2bf(v.y); o[2] = f2bf(v.z); o[3] = f2bf(v.w);
    dst[i] = o;
  }
}

// Convert 4 weight matrices fp32 -> bf16
__global__ __launch_bounds__(256) void cvtW_f32_bf16(
    const float4* __restrict__ s0, const float4* __restrict__ s1,
    const float4* __restrict__ s2, const float4* __restrict__ s3,
    ushort4v* __restrict__ d0, ushort4v* __restrict__ d1,
    ushort4v* __restrict__ d2, ushort4v* __restrict__ d3, int n4)
{
  const float4* src = (blockIdx.y == 0) ? s0 : (blockIdx.y == 1) ? s1 : (blockIdx.y == 2) ? s2 : s3;
  ushort4v*    dst  = (blockIdx.y == 0) ? d0 : (blockIdx.y == 1) ? d1 : (blockIdx.y == 2) ? d2 : d3;
  int idx = blockIdx.x * blockDim.x + threadIdx.x;
  int stride = gridDim.x * blockDim.x;
  for (int i = idx; i < n4; i += stride) {
    float4 v = src[i];
    ushort4v o;
    o[0] = f2bf(v.x); o[1] = f2bf(v.y); o[2] = f2bf(v.z); o[3] = f2bf(v.w);
    dst[i] = o;
  }
}

// out[m,n] = sum_k X[m,k]*W[n,k] + bias[n].
// v3: double-buffered 2-phase K-loop (issue-early / drain-late, one barrier per
// step) + XCD-bijective block swizzle (4 n-blocks sharing an A-tile colocate on
// one XCD; W L2-resident per XCD) + launch_bounds(256,2) so VGPR budget is 256
// (v2's (256,4) capped at 128 = right at the acc(64)+frag(32)+addr(~25) cliff).
// LDS 64 KB -> 2 blocks/CU, which (256,2) matches exactly.
// LDS layout [row][chunk]: stored chunk c holds source chunk c ^ (row&7) -> ~conflict-free b128.
#define NXB (Ee/128)      // 4 n-blocks
#define NYB (NTOK/128)    // 128 m-blocks
template <bool F32OUT>
__global__ __launch_bounds__(256, 2) void gemm_nt_bias3(
    const unsigned short* __restrict__ X0, const unsigned short* __restrict__ X1,
    const unsigned short* __restrict__ X2,
    const unsigned short* __restrict__ W0, const unsigned short* __restrict__ W1,
    const unsigned short* __restrict__ W2,
    const float* __restrict__ bias0, const float* __restrict__ bias1,
    const float* __restrict__ bias2,
    void* __restrict__ out0, void* __restrict__ out1, void* __restrict__ out2)
{
  const int z = blockIdx.z;
  const unsigned short* X = (z == 0) ? X0 : (z == 1) ? X1 : X2;
  const unsigned short* W = (z == 0) ? W0 : (z == 1) ? W1 : W2;
  const float* bias        = (z == 0) ? bias0 : (z == 1) ? bias1 : bias2;
  void* outv               = (z == 0) ? out0 : (z == 1) ? out1 : out2;

  __shared__ unsigned short As[2][128 * 64];   // 2 x 16 KB
  __shared__ unsigned short Bs[2][128 * 64];   // 2 x 16 KB

  // XCD-bijective swizzle within this z-slab (512 blocks, 512%8==0 -> clean):
  // default linear id round-robins XCDs; remap so XCD g owns original ids
  // [g*64, (g+1)*64) = 16 consecutive y-groups x all 4 x-siblings.
  const int id   = blockIdx.x + NXB * blockIdx.y;
  const int orig = (id & 7) * (NXB * NYB / 8) + (id >> 3);
  const int m_blk = (orig >> 2) * 128;
  const int n_blk = (orig & (NXB - 1)) * 128;

  const int K = Ee, N = Ee;
  const int lane = threadIdx.x & 63;
  const int wave = threadIdx.x >> 6;
  const int r16  = lane & 15;
  const int oct  = lane >> 4;
  const int wm = (wave >> 1) * 64;
  const int wn = (wave & 1) * 64;

  const int row8  = lane >> 3;
  const int chSrc = (lane & 7) ^ row8;

  floatx4 acc[4][4];
  #pragma unroll
  for (int a = 0; a < 4; ++a)
    #pragma unroll
    for (int b = 0; b < 4; ++b)
      acc[a][b] = (floatx4)(0.0f);

  // prologue: stage tile 0 into buffer 0
  #pragma unroll
  for (int t = 0; t < 4; ++t) {
    const int rbase = t * 32 + wave * 8;
    __builtin_amdgcn_global_load_lds(
        (const __attribute__((address_space(1))) unsigned int*)(X + (size_t)(m_blk + rbase + row8) * K + chSrc * 8),
        (__attribute__((address_space(3))) unsigned int*)(As[0] + rbase * 64), 16, 0, 0);
    __builtin_amdgcn_global_load_lds(
        (const __attribute__((address_space(1))) unsigned int*)(W + (size_t)(n_blk + rbase + row8) * K + chSrc * 8),
        (__attribute__((address_space(3))) unsigned int*)(Bs[0] + rbase * 64), 16, 0, 0);
  }
  __syncthreads();

  #pragma unroll
  for (int kt = 0; kt < 8; ++kt) {
    const int cur = kt & 1;
    // issue next-tile loads early: HBM latency hides under this tile's compute
    if (kt < 7) {
      const int kb = (kt + 1) * 64;
      #pragma unroll
      for (int t = 0; t < 4; ++t) {
        const int rbase = t * 32 + wave * 8;
        __builtin_amdgcn_global_load_lds(
            (const __attribute__((address_space(1))) unsigned int*)(X + (size_t)(m_blk + rbase + row8) * K + kb + chSrc * 8),
            (__attribute__((address_space(3))) unsigned int*)(As[cur ^ 1] + rbase * 64), 16, 0, 0);
        __builtin_amdgcn_global_load_lds(
            (const __attribute__((address_space(1))) unsigned int*)(W + (size_t)(n_blk + rbase + row8) * K + kb + chSrc * 8),
            (__attribute__((address_space(3))) unsigned int*)(Bs[cur ^ 1] + rbase * 64), 16, 0, 0);
      }
    }

    #pragma unroll
    for (int s = 0; s < 2; ++s) {
      bf16x8 af[4], bfq[4];
      #pragma unroll
      for (int mi = 0; mi < 4; ++mi) {
        const int row = wm + mi * 16 + r16;
        af[mi] = *(const bf16x8*)(As[cur] + row * 64 + ((s * 4 + oct) ^ (r16 & 7)) * 8);
      }
      #pragma unroll
      for (int ni = 0; ni < 4; ++ni) {
        const int row = wn + ni * 16 + r16;
        bfq[ni] = *(const bf16x8*)(Bs[cur] + row * 64 + ((s * 4 + oct) ^ (r16 & 7)) * 8);
      }
      #pragma unroll
      for (int mi = 0; mi < 4; ++mi)
        #pragma unroll
        for (int ni = 0; ni < 4; ++ni)
          acc[mi][ni] = __builtin_amdgcn_mfma_f32_16x16x32_bf16(af[mi], bfq[ni], acc[mi][ni], 0, 0, 0);
    }
    // drain next-tile loads + release this buffer for overwrite
    __syncthreads();
  }

  float bv[4];
  #pragma unroll
  for (int ni = 0; ni < 4; ++ni) bv[ni] = bias[n_blk + wn + ni * 16 + r16];

  #pragma unroll
  for (int mi = 0; mi < 4; ++mi)
    #pragma unroll
    for (int ni = 0; ni < 4; ++ni)
      #pragma unroll
      for (int r = 0; r < 4; ++r) {
        const int m = m_blk + wm + mi * 16 + oct * 4 + r;
        const int n = n_blk + wn + ni * 16 + r16;
        const float val = acc[mi][ni][r] + bv[ni];
        if (F32OUT) __builtin_nontemporal_store(val, (float*)outv + (size_t)m * N + n);
        else        ((unsigned short*)outv)[(size_t)m * N + n] = f2bf(val);
      }
}

// ============================= attn v2 ========================================
// Swapped-QK + two-pass online softmax. Per (b,h,c) slice: 2 blocks x 8 waves;
// wave handles stripe pair (rt0, 31-rt0), 16 q-rows each.
//
// Layout (swapped mfma(K,Q)): lane (r16,oct) owns row i=I+r16; reg r holds
// j = 16ct + 4oct + r (4 CONSECUTIVE j -> float4 attn stores; j%4==r so the
// strided mask collapses to "r==0 => j<=i", others window-only).
//
// Pass A: online max/sum only (no P-state array!) -> ~100 regs total ->
// __launch_bounds__(512,4) => 2 blocks/CU = 16 waves/CU.
// Pass B: recompute scores, p = exp(s + c), c = -m - log(l); nontemporal
// float4 attn stores; P->A-frag via 2x ds_write_b64 + 1x ds_read_b128 per jc.
// PV swapped (mfma(V^T,P)) -> ctx lands 4-consecutive-d per lane -> 8B stores.
//
// V^T staging: wave w owns d-rows w*8..w*8+7; lane packs j-pair into dword
// writes -> 2-way banks.
__global__ __launch_bounds__(512, 4) void attn_kernel(
    const unsigned short* __restrict__ Q,
    const unsigned short* __restrict__ Kb,
    const unsigned short* __restrict__ V,
    float* __restrict__ attn_out,           // write-only
    unsigned short* __restrict__ ctx)
{
  __shared__ unsigned short VT[HDd][Ss];        // 64 KB, [d][j^((d&7)<<3)]
  __shared__ unsigned short scr[8][16 * RS];    // 10 KB per-wave P scratch

  const int slice = blockIdx.x;            // (b*H + h)*C + c
  const int c  = slice & (Cc - 1);
  const int bh = slice >> 3;
  const int h  = bh & (Hh - 1);
  const int b  = bh >> 3;
  const size_t tokBase  = (size_t)(b * Cc + c) * Ss;
  const size_t attnBase = (size_t)slice * Ss * Ss;

  const int tid  = threadIdx.x;
  const int lane = tid & 63;
  const int wave = tid >> 6;
  const int r16  = lane & 15;
  const int oct  = lane >> 4;
  unsigned short* sw = scr[wave];

  // ---- stage V^T: wave w -> d rows w*8..w*8+7; lane jp -> j pair (2jp,2jp+1)
  {
    const int d0 = wave * 8;
    const unsigned short* vbase = V + tokBase * Ee + h * HDd + d0;
    #pragma unroll
    for (int pass = 0; pass < 4; ++pass) {
      const int j0 = pass * 128 + lane * 2;
      const uint4 ra = *(const uint4*)(vbase + (size_t)j0 * Ee);
      const uint4 rb = *(const uint4*)(vbase + (size_t)(j0 + 1) * Ee);
      const unsigned int aw[4] = {ra.x, ra.y, ra.z, ra.w};
      const unsigned int bw[4] = {rb.x, rb.y, rb.z, rb.w};
      #pragma unroll
      for (int k = 0; k < 8; ++k) {
        const unsigned int av = (k & 1) ? (aw[k >> 1] >> 16) : (aw[k >> 1] & 0xffffu);
        const unsigned int bv = (k & 1) ? (bw[k >> 1] >> 16) : (bw[k >> 1] & 0xffffu);
        *(unsigned int*)(&VT[d0 + k][j0 ^ (k << 3)]) = av | (bv << 16);  // pair stays adjacent (swz flips bits>=3)
      }
    }
  }
  __syncthreads();

  const int rt0 = 2 * wave + blockIdx.y;   // 0..15
  for (int t = 0; t < 2; ++t) {
    const int rt = t ? (31 - rt0) : rt0;   // pair sums to 31 -> balanced waves
    const int I  = rt * 16;
    const int i  = I + r16;

    const unsigned short* qrow = Q + (tokBase + i) * Ee + h * HDd + oct * 8;
    const bf16x8 qa0 = *(const bf16x8*)(qrow);
    const bf16x8 qa1 = *(const bf16x8*)(qrow + 32);
    const unsigned short* kbase = Kb + (tokBase + r16) * Ee + h * HDd + oct * 8;
    const int ij0 = i - 4 * oct;           // di(r) = ij0 - 16ct - r

    // ---- pass A: online max/sum (natural-log domain), no score storage ----
    float m_a = -INFINITY, l_a = 0.0f, m_b = -INFINITY, l_b = 0.0f;
    const int farEnd = rt - 2;             // far region = [0, farEnd)
    int ct = 0;
    for (; ct + 1 < farEnd; ct += 2) {
      const unsigned short* kr0 = kbase + (size_t)ct * (16 * Ee);
      const unsigned short* kr1 = kbase + (size_t)(ct + 1) * (16 * Ee);
      const bf16x8 ka0 = *(const bf16x8*)(kr0);
      const bf16x8 ka1 = *(const bf16x8*)(kr0 + 32);
      const bf16x8 kc0 = *(const bf16x8*)(kr1);
      const bf16x8 kc1 = *(const bf16x8*)(kr1 + 32);
      floatx4 a = (floatx4)(0.0f), a2 = (floatx4)(0.0f);
      a  = __builtin_amdgcn_mfma_f32_16x16x32_bf16(ka0, qa0, a, 0, 0, 0);
      a  = __builtin_amdgcn_mfma_f32_16x16x32_bf16(ka1, qa1, a, 0, 0, 0);
      a2 = __builtin_amdgcn_mfma_f32_16x16x32_bf16(kc0, qa0, a2, 0, 0, 0);
      a2 = __builtin_amdgcn_mfma_f32_16x16x32_bf16(kc1, qa1, a2, 0, 0, 0);
      const float v0 = a[0] * 0.125f;
      const float w0 = a2[0] * 0.125f;
      float mn = fmaxf(m_a, v0);
      l_a = l_a * sexp(m_a - mn) + sexp(v0 - mn);
      m_a = mn;
      mn = fmaxf(m_b, w0);
      l_b = l_b * sexp(m_b - mn) + sexp(w0 - mn);
      m_b = mn;
    }
    for (; ct < farEnd; ++ct) {
      const unsigned short* krow = kbase + (size_t)ct * (16 * Ee);
      const bf16x8 kb0 = *(const bf16x8*)(krow);
      const bf16x8 kb1 = *(const bf16x8*)(krow + 32);
      floatx4 a = (floatx4)(0.0f);
      a = __builtin_amdgcn_mfma_f32_16x16x32_bf16(kb0, qa0, a, 0, 0, 0);
      a = __builtin_amdgcn_mfma_f32_16x16x32_bf16(kb1, qa1, a, 0, 0, 0);
      const float v0 = a[0] * 0.125f;
      const float mn = fmaxf(m_a, v0);
      l_a = l_a * sexp(m_a - mn) + sexp(v0 - mn);
      m_a = mn;
    }
    // near cts: full 4-value mask
    for (ct = (farEnd > 0 ? farEnd : 0); ct <= rt; ++ct) {
      const unsigned short* krow = kbase + (size_t)ct * (16 * Ee);
      const bf16x8 kb0 = *(const bf16x8*)(krow);
      const bf16x8 kb1 = *(const bf16x8*)(krow + 32);
      floatx4 a = (floatx4)(0.0f);
      a = __builtin_amdgcn_mfma_f32_16x16x32_bf16(kb0, qa0, a, 0, 0, 0);
      a = __builtin_amdgcn_mfma_f32_16x16x32_bf16(kb1, qa1, a, 0, 0, 0);
      const int dib = ij0 - 16 * ct;
      const float v0 = (dib >= 0)                   ? a[0] * 0.125f : -INFINITY;
      const float v1 = ((unsigned)(dib - 1) <= 32u) ? a[1] * 0.125f : -INFINITY;
      const float v2 = ((unsigned)(dib - 2) <= 32u) ? a[2] * 0.125f : -INFINITY;
      const float v3 = ((unsigned)(dib - 3) <= 32u) ? a[3] * 0.125f : -INFINITY;
      const float mx4 = fmaxf(fmaxf(v0, v1), fmaxf(v2, v3));
      const float mn = fmaxf(m_a, mx4);
      l_a = l_a * sexp(m_a - mn)
          + sexp(v0 - mn) + sexp(v1 - mn) + sexp(v2 - mn) + sexp(v3 - mn);
      m_a = mn;
    }
    // merge b-state, then across the 4 octs sharing this row (xor 16, 32)
    float m = fmaxf(m_a, m_b);
    float l = l_a * sexp(m_a - m) + l_b * sexp(m_b - m);
    #pragma unroll
    for (int msk = 16; msk <= 32; msk <<= 1) {
      const float mo = __shfl_xor(m, msk, 64);
      const float lo = __shfl_xor(l, msk, 64);
      const float mn = fmaxf(m, mo);
      l = l * sexp(m - mn) + lo * sexp(mo - mn);
      m = mn;
    }
    const float cc = -m - __logf(l);       // p = exp(s + cc), exact zeros when masked

    // ---- pass B: recompute scores, store attn (nt float4), feed PV ----
    const int jcMax = rt >> 1;
    floatx4 cacc[4];
    #pragma unroll
    for (int dt = 0; dt < 4; ++dt) cacc[dt] = (floatx4)(0.0f);
    float* attnRow = attn_out + attnBase + (size_t)i * Ss + oct * 4;
    unsigned short* swrow = sw + r16 * RS;

    for (int jc = 0; jc <= jcMax; ++jc) {
      #pragma unroll
      for (int h2 = 0; h2 < 2; ++h2) {
        const int ctp = 2 * jc + h2;
        float p0 = 0.0f, p1 = 0.0f, p2 = 0.0f, p3 = 0.0f;
        if (ctp <= rt) {
          const unsigned short* krow = kbase + (size_t)ctp * (16 * Ee);
          const bf16x8 kb0 = *(const bf16x8*)(krow);
          const bf16x8 kb1 = *(const bf16x8*)(krow + 32);
          floatx4 a = (floatx4)(0.0f);
          a = __builtin_amdgcn_mfma_f32_16x16x32_bf16(kb0, qa0, a, 0, 0, 0);
          a = __builtin_amdgcn_mfma_f32_16x16x32_bf16(kb1, qa1, a, 0, 0, 0);
          if (ctp < farEnd) {
            p0 = __expf(a[0] * 0.125f + cc);
          } else {
            const int dib = ij0 - 16 * ctp;
            if (dib >= 0)                   p0 = __expf(a[0] * 0.125f + cc);
            if ((unsigned)(dib - 1) <= 32u) p1 = __expf(a[1] * 0.125f + cc);
            if ((unsigned)(dib - 2) <= 32u) p2 = __expf(a[2] * 0.125f + cc);
            if ((unsigned)(dib - 3) <= 32u) p3 = __expf(a[3] * 0.125f + cc);
          }
        }
        __builtin_nontemporal_store((floatx4){p0, p1, p2, p3},
                                    (floatx4*)(attnRow + (size_t)ctp * 16));
        const unsigned int plo = (unsigned int)f2bf(p0) | ((unsigned int)f2bf(p1) << 16);
        const unsigned int phi = (unsigned int)f2bf(p2) | ((unsigned int)f2bf(p3) << 16);
        *(uint2*)(swrow + h2 * 16 + oct * 4) = make_uint2(plo, phi);
      }
      const bf16x8 pa = *(const bf16x8*)(swrow + oct * 8);
      #pragma unroll
      for (int dt = 0; dt < 4; ++dt) {
        const int d = dt * 16 + r16;
        const bf16x8 vb = *(const bf16x8*)(&VT[d][(jc * 32 + oct * 8) ^ ((d & 7) << 3)]);
        cacc[dt] = __builtin_amdgcn_mfma_f32_16x16x32_bf16(vb, pa, cacc[dt], 0, 0, 0);
      }
    }
    // zero tail beyond the causal stripe
    const floatx4 z4 = (floatx4)(0.0f);
    for (int ctz = 2 * (jcMax + 1); ctz < 32; ++ctz)
      __builtin_nontemporal_store(z4, (floatx4*)(attnRow + (size_t)ctz * 16));
    // ctx: lane holds 4 consecutive d per dt -> packed 8B stores
    #pragma unroll
    for (int dt = 0; dt < 4; ++dt) {
      const unsigned int lo = (unsigned int)f2bf(cacc[dt][0]) | ((unsigned int)f2bf(cacc[dt][1]) << 16);
      const unsigned int hi = (unsigned int)f2bf(cacc[dt][2]) | ((unsigned int)f2bf(cacc[dt][3]) << 16);
      *(uint2*)(ctx + (tokBase + i) * Ee + h * HDd + dt * 16 + oct * 4) = make_uint2(lo, hi);
    }
  }
}

extern "C" void kernel_launch(void* const* d_in, const int* in_sizes, int n_in,
                              void* d_out, int out_size, void* d_ws, size_t ws_size,
                              hipStream_t stream) {
  const float* query = (const float*)d_in[0];
  const float* key_  = (const float*)d_in[1];
  const float* value = (const float*)d_in[2];
  const float* Wq = (const float*)d_in[3];
  const float* bq = (const float*)d_in[4];
  const float* Wk = (const float*)d_in[5];
  const float* bk = (const float*)d_in[6];
  const float* Wv = (const float*)d_in[7];
  const float* bv = (const float*)d_in[8];
  const float* Wo = (const float*)d_in[9];
  const float* bo = (const float*)d_in[10];

  float* out  = (float*)d_out;                          // [B,C,S,E] fp32
  float* attn = out + (size_t)Bb*Cc*Ss*Ee;              // [B,H,C,S,S] fp32

  unsigned short* ws = (unsigned short*)d_ws;
  unsigned short* qb  = ws;
  unsigned short* kb  = qb  + (size_t)NTOK * Ee;
  unsigned short* vb  = kb  + (size_t)NTOK * Ee;
  unsigned short* Qw  = vb  + (size_t)NTOK * Ee;
  unsigned short* Kw  = Qw  + (size_t)NTOK * Ee;
  unsigned short* Vw  = Kw  + (size_t)NTOK * Ee;
  unsigned short* Cw  = Vw  + (size_t)NTOK * Ee;
  unsigned short* Wqb = Cw  + (size_t)NTOK * Ee;
  unsigned short* Wkb = Wqb + (size_t)Ee * Ee;
  unsigned short* Wvb = Wkb + (size_t)Ee * Ee;
  unsigned short* Wob = Wvb + (size_t)Ee * Ee;

  const int n4big = NTOK * Ee / 4;
  const int n4w   = Ee * Ee / 4;
  cvt3_f32_bf16<<<dim3(1024, 3), 256, 0, stream>>>(
      (const float4*)query, (const float4*)key_, (const float4*)value,
      (ushort4v*)qb, (ushort4v*)kb, (ushort4v*)vb, n4big);
  cvtW_f32_bf16<<<dim3(128, 4), 256, 0, stream>>>(
      (const float4*)Wq, (const float4*)Wk, (const float4*)Wv, (const float4*)Wo,
      (ushort4v*)Wqb, (ushort4v*)Wkb, (ushort4v*)Wvb, (ushort4v*)Wob, n4w);

  dim3 blk(256);
  // fused q/k/v projections: z = tensor index
  gemm_nt_bias3<false><<<dim3(NXB, NYB, 3), blk, 0, stream>>>(
      qb, kb, vb, Wqb, Wkb, Wvb, bq, bk, bv, Qw, Kw, Vw);

  attn_kernel<<<dim3(Bb*Hh*Cc, 2), 512, 0, stream>>>(Qw, Kw, Vw, attn, Cw);

  gemm_nt_bias3<true><<<dim3(NXB, NYB, 1), blk, 0, stream>>>(
      Cw, Cw, Cw, Wob, Wob, Wob, bo, bo, bo, out, out, out);
}